// Round 6
// baseline (359.395 us; speedup 1.0000x reference)
//
#include <hip/hip_runtime.h>
#include <hip/hip_bf16.h>

typedef __attribute__((ext_vector_type(8))) short short8;
typedef __attribute__((ext_vector_type(4))) short short4v;
typedef __attribute__((ext_vector_type(4))) float f32x4;
typedef __attribute__((ext_vector_type(16))) float f32x16;
typedef __bf16 bf16x8 __attribute__((ext_vector_type(8)));

#define DEVI static __device__ __forceinline__

DEVI short f2bs(float f) {
    union { __hip_bfloat16 h; short s; } u;
    u.h = __float2bfloat16(f);
    return u.s;
}

DEVI unsigned pk2(float a, float b) {
    unsigned lo = (unsigned short)f2bs(a);
    unsigned hi = (unsigned short)f2bs(b);
    return lo | (hi << 16);
}

DEVI f32x4 mfma16(short8 a, short8 b, f32x4 c) {
    return __builtin_amdgcn_mfma_f32_16x16x32_bf16(
        __builtin_bit_cast(bf16x8, a), __builtin_bit_cast(bf16x8, b), c, 0, 0, 0);
}

DEVI f32x16 mfma32(short8 a, short8 b, f32x16 c) {
    return __builtin_amdgcn_mfma_f32_32x32x16_bf16(
        __builtin_bit_cast(bf16x8, a), __builtin_bit_cast(bf16x8, b), c, 0, 0, 0);
}

// async global->LDS, 16B per lane; LDS dest = wave-uniform base + lane*16
DEVI void glds16(const short* g, short* l) {
    __builtin_amdgcn_global_load_lds((const __attribute__((address_space(1))) void*)g,
                                     (__attribute__((address_space(3))) void*)l, 16, 0, 0);
}

// Merged fp32->bf16 convert: blocks [0,8192) = 3 activations, [8192,9216) = 4 weights.
__global__ __launch_bounds__(256) void cvt_all(const float4* __restrict__ q,
                                               const float4* __restrict__ k,
                                               const float4* __restrict__ v,
                                               const float4* __restrict__ wq,
                                               const float4* __restrict__ wk,
                                               const float4* __restrict__ wv,
                                               const float4* __restrict__ wo,
                                               short4v* __restrict__ dq,
                                               short4v* __restrict__ dk,
                                               short4v* __restrict__ dv,
                                               short4v* __restrict__ dwq,
                                               short4v* __restrict__ dwk,
                                               short4v* __restrict__ dwv,
                                               short4v* __restrict__ dwo) {
    int bid = blockIdx.x;
    float4 x;
    short4v s;
    if (bid < 8192) {
        int i = bid * 256 + threadIdx.x;
        x = q[i]; s.x = f2bs(x.x); s.y = f2bs(x.y); s.z = f2bs(x.z); s.w = f2bs(x.w); dq[i] = s;
        x = k[i]; s.x = f2bs(x.x); s.y = f2bs(x.y); s.z = f2bs(x.z); s.w = f2bs(x.w); dk[i] = s;
        x = v[i]; s.x = f2bs(x.x); s.y = f2bs(x.y); s.z = f2bs(x.z); s.w = f2bs(x.w); dv[i] = s;
    } else {
        int i = (bid - 8192) * 256 + threadIdx.x;
        x = wq[i]; s.x = f2bs(x.x); s.y = f2bs(x.y); s.z = f2bs(x.z); s.w = f2bs(x.w); dwq[i] = s;
        x = wk[i]; s.x = f2bs(x.x); s.y = f2bs(x.y); s.z = f2bs(x.z); s.w = f2bs(x.w); dwk[i] = s;
        x = wv[i]; s.x = f2bs(x.x); s.y = f2bs(x.y); s.z = f2bs(x.z); s.w = f2bs(x.w); dwv[i] = s;
        x = wo[i]; s.x = f2bs(x.x); s.y = f2bs(x.y); s.z = f2bs(x.z); s.w = f2bs(x.w); dwo[i] = s;
    }
}

// Shared GEMM body: C[m][n] = sum_k A[m][k]*B[n][k], tile 128x128, K=1024.
template <typename EpiT>
DEVI void gemm_body(const short* A, const short* Bw, short* smem, int m0, int n0, EpiT epi) {
    short* As = smem;
    short* Bs = smem + 8192;
    const int t = threadIdx.x;
    const int lane = t & 63, w = t >> 6;
    const int col = lane & 15, quad = lane >> 4;
    const int wm = (w & 1) * 64, wn = (w >> 1) * 64;

    f32x4 acc[4][4];
#pragma unroll
    for (int i = 0; i < 4; ++i)
#pragma unroll
        for (int j = 0; j < 4; ++j) acc[i][j] = (f32x4){0.f, 0.f, 0.f, 0.f};

    for (int kt = 0; kt < 16; ++kt) {
        const int k0 = kt * 64;
#pragma unroll
        for (int j = 0; j < 4; ++j) {
            int cbase = (j * 4 + w) * 64;
            int c = cbase + lane;
            int row = c >> 3, kc = (c & 7) ^ (row & 7);
            glds16(A + (size_t)(m0 + row) * 1024 + k0 + kc * 8, As + cbase * 8);
        }
#pragma unroll
        for (int j = 0; j < 4; ++j) {
            int cbase = (j * 4 + w) * 64;
            int c = cbase + lane;
            int row = c >> 3, kc = (c & 7) ^ (row & 7);
            glds16(Bw + (size_t)(n0 + row) * 1024 + k0 + kc * 8, Bs + cbase * 8);
        }
        __syncthreads();
#pragma unroll
        for (int ks = 0; ks < 2; ++ks) {
            short8 a[4], b[4];
#pragma unroll
            for (int i = 0; i < 4; ++i) {
                int row = wm + i * 16 + col;
                int kc = (ks * 4 + quad) ^ (col & 7);
                a[i] = *(const short8*)(As + (row * 8 + kc) * 8);
            }
#pragma unroll
            for (int i = 0; i < 4; ++i) {
                int row = wn + i * 16 + col;
                int kc = (ks * 4 + quad) ^ (col & 7);
                b[i] = *(const short8*)(Bs + (row * 8 + kc) * 8);
            }
#pragma unroll
            for (int mi = 0; mi < 4; ++mi)
#pragma unroll
                for (int ni = 0; ni < 4; ++ni)
                    acc[mi][ni] = mfma16(a[mi], b[ni], acc[mi][ni]);
        }
        __syncthreads();
    }
    epi(acc, wm, wn, col, quad);
}

// Fused Q/K/V projection: blockIdx.z selects which projection.
__global__ __launch_bounds__(256) void qkv_gemm(const short* __restrict__ xq,
                                                const short* __restrict__ xk,
                                                const short* __restrict__ xv,
                                                const short* __restrict__ wq,
                                                const short* __restrict__ wk,
                                                const short* __restrict__ wv,
                                                short* __restrict__ qp,
                                                short* __restrict__ kp,
                                                short* __restrict__ vpt, float qscale) {
    __shared__ __align__(16) short smem[17408];  // staging 16384 | T 128x136
    const int z = blockIdx.z;
    const int m0 = blockIdx.y * 128, n0 = blockIdx.x * 128;
    const short* A = (z == 0) ? xq : (z == 1) ? xk : xv;
    const short* W = (z == 0) ? wq : (z == 1) ? wk : wv;

    if (z < 2) {
        short* outs = (z == 0) ? qp : kp;
        const float scale = (z == 0) ? qscale : 1.0f;
        gemm_body(A, W, smem, m0, n0, [&](f32x4 (&acc)[4][4], int wm, int wn, int col, int quad) {
            short* T = smem;  // [128 m][136 n-padded]
#pragma unroll
            for (int mi = 0; mi < 4; ++mi)
#pragma unroll
                for (int ni = 0; ni < 4; ++ni)
#pragma unroll
                    for (int r = 0; r < 4; ++r)
                        T[(wm + mi * 16 + quad * 4 + r) * 136 + wn + ni * 16 + col] =
                            f2bs(acc[mi][ni][r] * scale);
            __syncthreads();
            int t = threadIdx.x;
            int ml = t >> 1, nh = (t & 1) * 64;
            int m = m0 + ml;                    // b*2048+s
            int b = m >> 11, s = m & 2047;
#pragma unroll
            for (int j = 0; j < 8; ++j) {
                int n = n0 + nh + j * 8;        // h*64+dk
                short8 vv = *(const short8*)(T + ml * 136 + nh + j * 8);
                size_t off = ((size_t)(b * 16 + (n >> 6)) * 2048 + s) * 64 + (n & 63);
                *(short8*)(outs + off) = vv;
            }
        });
    } else {
        gemm_body(A, W, smem, m0, n0, [&](f32x4 (&acc)[4][4], int wm, int wn, int col, int quad) {
            short* T = smem;  // [128 n][132 m]
#pragma unroll
            for (int mi = 0; mi < 4; ++mi)
#pragma unroll
                for (int ni = 0; ni < 4; ++ni) {
                    int n_l = wn + ni * 16 + col;
                    int m_l = wm + mi * 16 + quad * 4;
                    short4v sv;
                    sv.x = f2bs(acc[mi][ni][0]); sv.y = f2bs(acc[mi][ni][1]);
                    sv.z = f2bs(acc[mi][ni][2]); sv.w = f2bs(acc[mi][ni][3]);
                    *(short4v*)(T + n_l * 132 + m_l) = sv;
                }
            __syncthreads();
            int t = threadIdx.x;
            int nrow = t >> 1, mh = (t & 1) * 64;
            int b = m0 >> 11, s0 = m0 & 2047;
            size_t base = ((size_t)(b * 1024 + n0 + nrow)) * 2048 + s0 + mh;
#pragma unroll
            for (int j = 0; j < 16; ++j) {
                unsigned long long vv = *(const unsigned long long*)(T + nrow * 132 + mh + j * 4);
                *(unsigned long long*)(vpt + base + j * 4) = vv;
            }
        });
    }
}

__global__ __launch_bounds__(256) void out_gemm(const short* __restrict__ ao,
                                                const short* __restrict__ wo,
                                                float* __restrict__ outf) {
    __shared__ __align__(16) short smem[16896];
    const int m0 = blockIdx.y * 128, n0 = blockIdx.x * 128;
    gemm_body(ao, wo, smem, m0, n0, [&](f32x4 (&acc)[4][4], int wm, int wn, int col, int quad) {
#pragma unroll
        for (int mi = 0; mi < 4; ++mi)
#pragma unroll
            for (int ni = 0; ni < 4; ++ni)
#pragma unroll
                for (int r = 0; r < 4; ++r) {
                    int m = m0 + wm + mi * 16 + quad * 4 + r;
                    int n = n0 + wn + ni * 16 + col;
                    outf[(size_t)m * 1024 + n] = acc[mi][ni][r];
                }
    });
}

// Flash attention, 32x32 MFMA formulation. qp prescaled by 0.125*log2e.
// S^T = K Q^T via 32x32x16 (A=K m=key, B=Q n=q). C-layout: q=lane&31,
// key=(reg&3)+8*(reg>>2)+4*half. P=exp2(S^T) -> PV A-operand (m=q=lane&31,
// k=half*8+j) via 8 packed half-wave shfl_xor(32) per 32-key subtile — no LDS.
// PV: B = V^T frag from Vs (n=dk=lane&31, k=key). LDS 32 KB, zero P traffic.
__global__ __launch_bounds__(256, 4) void flash_attn(const short* __restrict__ qp,
                                                     const short* __restrict__ kp,
                                                     const short* __restrict__ vpt,
                                                     short* __restrict__ ao) {
    __shared__ __align__(16) short smem[16384];  // Ks 8192 | Vs 8192
    short* Ks = smem;
    short* Vs = smem + 8192;

    const int t = threadIdx.x, lane = t & 63, w = t >> 6;
    const int l31 = lane & 31, half = lane >> 5;
    const int bh = blockIdx.x, q0 = blockIdx.y * 128;
    const short* qb = qp + (size_t)bh * 2048 * 64;
    const short* kb = kp + (size_t)bh * 2048 * 64;
    const short* vb = vpt + (size_t)bh * 64 * 2048;

    // stage Q tile (swizzled) into Ks, pull B-operand frags: n=q=w*32+l31, k=ks*16+half*8
#pragma unroll
    for (int j = 0; j < 4; ++j) {
        int cbase = (j * 4 + w) * 64;
        int c = cbase + lane;
        int row = c >> 3, kc = (c & 7) ^ (row & 7);
        glds16(qb + (size_t)(q0 + row) * 64 + kc * 8, Ks + cbase * 8);
    }
    __syncthreads();
    short8 bQ[4];
    {
        int row = w * 32 + l31;
#pragma unroll
        for (int ks = 0; ks < 4; ++ks) {
            int kc = (ks * 2 + half) ^ (row & 7);
            bQ[ks] = *(const short8*)(Ks + (row * 8 + kc) * 8);
        }
    }
    __syncthreads();

    f32x16 acc[2] = {};
    float l_r = 0.f;

    for (int kt = 0; kt < 16; ++kt) {
        // stage K tile: 128 keys x 64 dk
#pragma unroll
        for (int j = 0; j < 4; ++j) {
            int cbase = (j * 4 + w) * 64;
            int c = cbase + lane;
            int row = c >> 3, kc = (c & 7) ^ (row & 7);
            glds16(kb + (size_t)(kt * 128 + row) * 64 + kc * 8, Ks + cbase * 8);
        }
        // stage V tile: 64 dk x 128 keys
#pragma unroll
        for (int j = 0; j < 4; ++j) {
            int m = w * 4 + j;
            int dk = m * 4 + (lane >> 4);
            int sc = (lane & 15) ^ (dk & 15);
            glds16(vb + (size_t)dk * 2048 + kt * 128 + sc * 8, Vs + m * 512);
        }
        __syncthreads();

#pragma unroll
        for (int sub = 0; sub < 4; ++sub) {  // 32-key subtiles
            f32x16 st = {};
            {
                int row = sub * 32 + l31;
#pragma unroll
                for (int ks = 0; ks < 4; ++ks) {
                    int kc = (ks * 2 + half) ^ (row & 7);
                    short8 aK = *(const short8*)(Ks + (row * 8 + kc) * 8);
                    st = mfma32(aK, bQ[ks], st);
                }
            }
            // P = exp2(S^T); pack reg pairs; half-wave swap
            unsigned u[8], x[8];
#pragma unroll
            for (int j = 0; j < 8; ++j) {
                float p0 = __builtin_amdgcn_exp2f(st[2 * j]);
                float p1 = __builtin_amdgcn_exp2f(st[2 * j + 1]);
                l_r += p0 + p1;
                u[j] = pk2(p0, p1);
            }
#pragma unroll
            for (int j = 0; j < 8; ++j) x[j] = __shfl_xor(u[j], 32);
            union U4 { unsigned u[4]; short8 s; } fa, fb;
            fa.u[0] = half ? x[2] : u[0];
            fa.u[1] = half ? x[3] : u[1];
            fa.u[2] = half ? u[2] : x[0];
            fa.u[3] = half ? u[3] : x[1];
            fb.u[0] = half ? x[6] : u[4];
            fb.u[1] = half ? x[7] : u[5];
            fb.u[2] = half ? u[6] : x[4];
            fb.u[3] = half ? u[7] : x[5];
            // O += P V : two dk-blocks x two 16-key sets
#pragma unroll
            for (int nb = 0; nb < 2; ++nb) {
                int dk = nb * 32 + l31;
#pragma unroll
                for (int kset = 0; kset < 2; ++kset) {
                    int kc = (sub * 4 + kset * 2 + half) ^ (dk & 15);
                    short8 bv = *(const short8*)(Vs + dk * 128 + kc * 8);
                    acc[nb] = mfma32(kset ? fb.s : fa.s, bv, acc[nb]);
                }
            }
        }
        __syncthreads();
    }

    // l lives per q=lane&31 split across halves; combine, invert, epilogue
    l_r += __shfl_xor(l_r, 32);
    float inv = 1.0f / l_r;
    const int b = bh >> 4, hd = bh & 15;
#pragma unroll
    for (int nb = 0; nb < 2; ++nb)
#pragma unroll
        for (int j = 0; j < 16; ++j) {
            int m = (j & 3) + 8 * (j >> 2) + 4 * half;
            float iq = __shfl(inv, m);
            int q = q0 + w * 32 + m;
            ao[((size_t)(b * 2048 + q)) * 1024 + hd * 64 + nb * 32 + l31] =
                f2bs(acc[nb][j] * iq);
        }
}

extern "C" void kernel_launch(void* const* d_in, const int* in_sizes, int n_in,
                              void* d_out, int out_size, void* d_ws, size_t ws_size,
                              hipStream_t stream) {
    const float* q  = (const float*)d_in[0];
    const float* k  = (const float*)d_in[1];
    const float* v  = (const float*)d_in[2];
    const float* Wq = (const float*)d_in[3];
    const float* Wk = (const float*)d_in[4];
    const float* Wv = (const float*)d_in[5];
    const float* Wo = (const float*)d_in[6];
    float* out = (float*)d_out;

    short* ws = (short*)d_ws;
    const size_t SZ = (size_t)64 * 2048 * 64;  // 8,388,608
    const size_t WZ = (size_t)1024 * 1024;
    short* xq  = ws;               // later: ao
    short* xk  = ws + SZ;          // later: vpt
    short* xv  = ws + 2 * SZ;
    short* qp  = ws + 3 * SZ;
    short* kp  = ws + 4 * SZ;
    short* wqb = ws + 5 * SZ;
    short* wkb = wqb + WZ;
    short* wvb = wqb + 2 * WZ;
    short* wob = wqb + 3 * WZ;
    short* ao  = xq;
    short* vpt = xk;

    const float QSCALE = 0.125f * 1.44269504088896f;  // 1/sqrt(64) * log2(e)

    cvt_all<<<dim3(9216), dim3(256), 0, stream>>>(
        (const float4*)q, (const float4*)k, (const float4*)v, (const float4*)Wq,
        (const float4*)Wk, (const float4*)Wv, (const float4*)Wo, (short4v*)xq, (short4v*)xk,
        (short4v*)xv, (short4v*)wqb, (short4v*)wkb, (short4v*)wvb, (short4v*)wob);
    dim3 blk(256);
    qkv_gemm<<<dim3(8, 64, 3), blk, 0, stream>>>(xq, xk, xv, wqb, wkb, wvb, qp, kp, vpt, QSCALE);
    flash_attn<<<dim3(64, 16), blk, 0, stream>>>(qp, kp, vpt, ao);
    out_gemm<<<dim3(8, 64), blk, 0, stream>>>(ao, wob, out);
}